// Round 1
// baseline (80.575 us; speedup 1.0000x reference)
//
#include <hip/hip_runtime.h>
#include <math.h>

#define D_MODEL 128
#define EDGE_DIM 9
#define HIDDEN 256
#define BATCH 2
#define NN 512

#define ROWS 8   // rows per block in kernel 1
#define TI 4     // i-tile in kernel 2
#define TJ 64    // j-tile in kernel 2

// ---------------------------------------------------------------------------
// Kernel 1: per-node projections pi = z@We_i + be1, pj = z@We_j, and the
// organ head sigmoid(relu(z@Wo1+bo1)@Wo2+bo2).
// grid = (B*N)/ROWS blocks, 256 threads (one thread per hidden unit h).
// ---------------------------------------------------------------------------
__global__ __launch_bounds__(256) void node_proj_kernel(
    const float* __restrict__ z,      // (B*N, 128)
    const float* __restrict__ Wo1,    // (128,256)
    const float* __restrict__ bo1,    // (256)
    const float* __restrict__ Wo2,    // (256,1)
    const float* __restrict__ bo2,    // (1)
    const float* __restrict__ We_i,   // (128,256)
    const float* __restrict__ We_j,   // (128,256)
    const float* __restrict__ be1,    // (256)
    float* __restrict__ organ_out,    // (B*N)
    float* __restrict__ pi,           // (B*N,256)  includes +be1
    float* __restrict__ pj)           // (B*N,256)
{
    __shared__ float z_s[ROWS][D_MODEL];
    __shared__ float red_s[4][ROWS];

    const int t  = threadIdx.x;
    const int r0 = blockIdx.x * ROWS;

    for (int idx = t; idx < ROWS * D_MODEL; idx += 256) {
        z_s[idx >> 7][idx & 127] = z[r0 * D_MODEL + idx];
    }
    __syncthreads();

    const int h = t;
    float accO[ROWS], accI[ROWS], accJ[ROWS];
    const float b1 = bo1[h];
    const float be = be1[h];
#pragma unroll
    for (int g = 0; g < ROWS; ++g) { accO[g] = b1; accI[g] = be; accJ[g] = 0.f; }

    for (int d = 0; d < D_MODEL; ++d) {
        const float w1 = Wo1[d * HIDDEN + h];
        const float wi = We_i[d * HIDDEN + h];
        const float wj = We_j[d * HIDDEN + h];
#pragma unroll
        for (int g = 0; g < ROWS; ++g) {
            const float zv = z_s[g][d];
            accO[g] = fmaf(zv, w1, accO[g]);
            accI[g] = fmaf(zv, wi, accI[g]);
            accJ[g] = fmaf(zv, wj, accJ[g]);
        }
    }

    const float wo2  = Wo2[h];
    const int   lane = t & 63;
    const int   wave = t >> 6;

#pragma unroll
    for (int g = 0; g < ROWS; ++g) {
        pi[(r0 + g) * HIDDEN + h] = accI[g];
        pj[(r0 + g) * HIDDEN + h] = accJ[g];
        float v = fmaxf(accO[g], 0.f) * wo2;
#pragma unroll
        for (int s = 32; s > 0; s >>= 1) v += __shfl_down(v, s, 64);
        if (lane == 0) red_s[wave][g] = v;
    }
    __syncthreads();

    if (t < ROWS) {
        const float s = red_s[0][t] + red_s[1][t] + red_s[2][t] + red_s[3][t] + bo2[0];
        organ_out[r0 + t] = 1.f / (1.f + expf(-s));
    }
}

// ---------------------------------------------------------------------------
// Kernel 2: fused edge head.
// grid = (N/TI) * (N/TJ) = 128*8 = 1024 blocks, 256 threads = 4 waves.
// Wave w handles j = j0 + w*16 + q. Lane owns h = lane*4 + k (k=0..3) so all
// per-h loads are float4-coalesced. pe = E[i,j,:]@We_e computed once per
// (i,j), reused across b. Per-output 64-lane shfl reduce; sums parked in LDS;
// parallel sigmoid*mask epilogue with coalesced stores.
// ---------------------------------------------------------------------------
__global__ __launch_bounds__(256) void edge_kernel(
    const float* __restrict__ E,     // (N,N,9)
    const int*   __restrict__ mask,  // (N,N)
    const float* __restrict__ We_e,  // (9,256)
    const float* __restrict__ We2,   // (256,1)
    const float* __restrict__ be2,   // (1)
    const float* __restrict__ pi,    // (B*N,256)
    const float* __restrict__ pj,    // (B*N,256)
    float* __restrict__ edge_out)    // (B,N,N)
{
    __shared__ float E_s[TI][TJ][EDGE_DIM];
    __shared__ float sums_s[BATCH * TI * TJ];   // [b][ii][jl]

    const int t    = threadIdx.x;
    const int lane = t & 63;
    const int wave = t >> 6;
    const int bi   = blockIdx.x;
    const int i0   = (bi >> 3) * TI;   // 128 i-blocks
    const int j0   = (bi & 7) * TJ;    // 8 j-blocks

    // Stage E tile: TI rows of TJ*9 = 576 contiguous floats each.
#pragma unroll
    for (int ii = 0; ii < TI; ++ii) {
        float* dst = &E_s[ii][0][0];
        const float* src = &E[((size_t)(i0 + ii) * NN + j0) * EDGE_DIM];
        for (int idx = t; idx < TJ * EDGE_DIM; idx += 256) dst[idx] = src[idx];
    }

    // Per-lane weights/activations, h = lane*4 + k.
    float4 wee[EDGE_DIM];
    const float4* We_e4 = (const float4*)We_e;
#pragma unroll
    for (int d = 0; d < EDGE_DIM; ++d) wee[d] = We_e4[d * 64 + lane];
    const float4 w2 = ((const float4*)We2)[lane];

    float4 pir[BATCH][TI];
#pragma unroll
    for (int b = 0; b < BATCH; ++b)
#pragma unroll
        for (int ii = 0; ii < TI; ++ii)
            pir[b][ii] = ((const float4*)pi)[(size_t)(b * NN + i0 + ii) * 64 + lane];

    __syncthreads();

    for (int q = 0; q < 16; ++q) {
        const int jl = wave * 16 + q;
        const int j  = j0 + jl;
        float4 pjr[BATCH];
#pragma unroll
        for (int b = 0; b < BATCH; ++b)
            pjr[b] = ((const float4*)pj)[(size_t)(b * NN + j) * 64 + lane];

#pragma unroll
        for (int ii = 0; ii < TI; ++ii) {
            float4 pe = {0.f, 0.f, 0.f, 0.f};
#pragma unroll
            for (int d = 0; d < EDGE_DIM; ++d) {
                const float ev = E_s[ii][jl][d];
                pe.x = fmaf(ev, wee[d].x, pe.x);
                pe.y = fmaf(ev, wee[d].y, pe.y);
                pe.z = fmaf(ev, wee[d].z, pe.z);
                pe.w = fmaf(ev, wee[d].w, pe.w);
            }
#pragma unroll
            for (int b = 0; b < BATCH; ++b) {
                float4 v;
                v.x = fmaxf(pir[b][ii].x + pjr[b].x + pe.x, 0.f);
                v.y = fmaxf(pir[b][ii].y + pjr[b].y + pe.y, 0.f);
                v.z = fmaxf(pir[b][ii].z + pjr[b].z + pe.z, 0.f);
                v.w = fmaxf(pir[b][ii].w + pjr[b].w + pe.w, 0.f);
                float acc = fmaf(v.x, w2.x, fmaf(v.y, w2.y, fmaf(v.z, w2.z, v.w * w2.w)));
#pragma unroll
                for (int s = 32; s > 0; s >>= 1) acc += __shfl_down(acc, s, 64);
                if (lane == 0) sums_s[b * (TI * TJ) + ii * TJ + jl] = acc;
            }
        }
    }
    __syncthreads();

    const float b2 = be2[0];
#pragma unroll
    for (int o = t; o < BATCH * TI * TJ; o += 256) {
        const int b   = o >> 8;          // TI*TJ = 256
        const int rem = o & 255;
        const int ii  = rem >> 6;        // TJ = 64
        const int jl  = rem & 63;
        const int i = i0 + ii, j = j0 + jl;
        const float s = sums_s[o] + b2;
        float p = 1.f / (1.f + expf(-s));
        p *= (float)mask[i * NN + j];
        edge_out[((size_t)b * NN + i) * NN + j] = p;
    }
}

extern "C" void kernel_launch(void* const* d_in, const int* in_sizes, int n_in,
                              void* d_out, int out_size, void* d_ws, size_t ws_size,
                              hipStream_t stream) {
    const float* z    = (const float*)d_in[0];   // (B,N,128)
    const float* E    = (const float*)d_in[1];   // (N,N,9)
    const int*   mask = (const int*)  d_in[2];   // (N,N)
    const float* Wo1  = (const float*)d_in[3];
    const float* bo1  = (const float*)d_in[4];
    const float* Wo2  = (const float*)d_in[5];
    const float* bo2  = (const float*)d_in[6];
    const float* We_i = (const float*)d_in[7];
    const float* We_j = (const float*)d_in[8];
    const float* We_e = (const float*)d_in[9];
    const float* be1  = (const float*)d_in[10];
    const float* We2  = (const float*)d_in[11];
    const float* be2  = (const float*)d_in[12];

    float* out_organ = (float*)d_out;                 // (B,N) = 1024
    float* out_edge  = out_organ + BATCH * NN;        // (B,N,N)

    float* pi = (float*)d_ws;                          // (B*N,256)
    float* pj = pi + (size_t)BATCH * NN * HIDDEN;      // (B*N,256)

    hipLaunchKernelGGL(node_proj_kernel,
                       dim3((BATCH * NN) / ROWS), dim3(256), 0, stream,
                       z, Wo1, bo1, Wo2, bo2, We_i, We_j, be1,
                       out_organ, pi, pj);

    hipLaunchKernelGGL(edge_kernel,
                       dim3((NN / TI) * (NN / TJ)), dim3(256), 0, stream,
                       E, mask, We_e, We2, be2, pi, pj, out_edge);
}

// Round 2
// 57.121 us; speedup vs baseline: 1.4106x; 1.4106x over previous
//
#include <hip/hip_runtime.h>
#include <math.h>

#define D_MODEL 128
#define EDGE_DIM 9
#define HIDDEN 256
#define BATCH 2
#define NN 512

#define ROWSN 4  // rows per block in kernel 1
#define TI 4     // i-tile in kernel 2
#define TJ 64    // j-tile in kernel 2

// ---------------------------------------------------------------------------
// Kernel 1: per-node projections pi = z@We_i + be1, pj = z@We_j, and the
// organ head sigmoid(relu(z@Wo1+bo1)@Wo2+bo2).
// grid = 256 blocks (all CUs), 256 threads. Thread t handles h = 2*(t&127)
// and h+1 (float2 weight loads), rows r0 + 2*(t>>7) + {0,1}.
// ---------------------------------------------------------------------------
__global__ __launch_bounds__(256) void node_proj_kernel(
    const float* __restrict__ z,      // (B*N, 128)
    const float* __restrict__ Wo1,    // (128,256)
    const float* __restrict__ bo1,    // (256)
    const float* __restrict__ Wo2,    // (256,1)
    const float* __restrict__ bo2,    // (1)
    const float* __restrict__ We_i,   // (128,256)
    const float* __restrict__ We_j,   // (128,256)
    const float* __restrict__ be1,    // (256)
    float* __restrict__ organ_out,    // (B*N)
    float* __restrict__ pi,           // (B*N,256)  includes +be1
    float* __restrict__ pj)           // (B*N,256)
{
    __shared__ float z_s[ROWSN][D_MODEL];
    __shared__ float red_s[ROWSN][2];

    const int t  = threadIdx.x;
    const int r0 = blockIdx.x * ROWSN;

    // stage ROWSN*128 = 512 floats with 256 threads (2 iters)
#pragma unroll
    for (int k = 0; k < 2; ++k) {
        const int idx = t + k * 256;
        z_s[idx >> 7][idx & 127] = z[r0 * D_MODEL + idx];
    }
    __syncthreads();

    const int h2   = t & 127;    // h = 2*h2, 2*h2+1
    const int half = t >> 7;     // rows r0 + 2*half + {0,1}

    const float2 b1 = *(const float2*)&bo1[2 * h2];
    const float2 be = *(const float2*)&be1[2 * h2];
    float2 accO[2], accI[2], accJ[2];
#pragma unroll
    for (int rr = 0; rr < 2; ++rr) {
        accO[rr] = b1; accI[rr] = be;
        accJ[rr].x = 0.f; accJ[rr].y = 0.f;
    }

    const float* zr0 = &z_s[2 * half][0];
    const float* zr1 = &z_s[2 * half + 1][0];

#pragma unroll 8
    for (int d = 0; d < D_MODEL; ++d) {
        const float2 w1 = *(const float2*)&Wo1 [d * HIDDEN + 2 * h2];
        const float2 wi = *(const float2*)&We_i[d * HIDDEN + 2 * h2];
        const float2 wj = *(const float2*)&We_j[d * HIDDEN + 2 * h2];
        const float z0 = zr0[d];
        const float z1 = zr1[d];
        accO[0].x = fmaf(z0, w1.x, accO[0].x); accO[0].y = fmaf(z0, w1.y, accO[0].y);
        accO[1].x = fmaf(z1, w1.x, accO[1].x); accO[1].y = fmaf(z1, w1.y, accO[1].y);
        accI[0].x = fmaf(z0, wi.x, accI[0].x); accI[0].y = fmaf(z0, wi.y, accI[0].y);
        accI[1].x = fmaf(z1, wi.x, accI[1].x); accI[1].y = fmaf(z1, wi.y, accI[1].y);
        accJ[0].x = fmaf(z0, wj.x, accJ[0].x); accJ[0].y = fmaf(z0, wj.y, accJ[0].y);
        accJ[1].x = fmaf(z1, wj.x, accJ[1].x); accJ[1].y = fmaf(z1, wj.y, accJ[1].y);
    }

    const float2 wo2 = *(const float2*)&Wo2[2 * h2];
    const int lane = t & 63;
    const int wave = t >> 6;     // half = wave>>1, h-half = wave&1

    float vrow[2];
#pragma unroll
    for (int rr = 0; rr < 2; ++rr) {
        const int row = r0 + 2 * half + rr;
        *(float2*)&pi[(size_t)row * HIDDEN + 2 * h2] = accI[rr];
        *(float2*)&pj[(size_t)row * HIDDEN + 2 * h2] = accJ[rr];
        vrow[rr] = fmaf(fmaxf(accO[rr].x, 0.f), wo2.x,
                        fmaxf(accO[rr].y, 0.f) * wo2.y);
    }

    // paired butterfly reduce: even lanes end with row rr=0, odd with rr=1
    float r  = (lane & 1) ? vrow[1] : vrow[0];
    float o_ = (lane & 1) ? vrow[0] : vrow[1];
    r += __shfl_xor(o_, 1, 64);
#pragma unroll
    for (int s = 2; s <= 32; s <<= 1) r += __shfl_xor(r, s, 64);
    if (lane < 2) red_s[2 * half + lane][wave & 1] = r;
    __syncthreads();

    if (t < ROWSN) {
        const float s = red_s[t][0] + red_s[t][1] + bo2[0];
        organ_out[r0 + t] = 1.f / (1.f + expf(-s));
    }
}

// ---------------------------------------------------------------------------
// Kernel 2: fused edge head.
// grid = 1024 blocks, 512 threads = 8 waves. Wave w handles jl = w*8+q.
// Lane owns h = lane*4+k. E staged padded 9->12 so each (ii,jl) row is three
// broadcast ds_read_b128. Paired-b butterfly reduce (one shfl tree for both
// batch outputs). Epilogue: one output per thread.
// ---------------------------------------------------------------------------
__global__ __launch_bounds__(512, 4) void edge_kernel(
    const float* __restrict__ E,     // (N,N,9)
    const int*   __restrict__ mask,  // (N,N)
    const float* __restrict__ We_e,  // (9,256)
    const float* __restrict__ We2,   // (256,1)
    const float* __restrict__ be2,   // (1)
    const float* __restrict__ pi,    // (B*N,256)
    const float* __restrict__ pj,    // (B*N,256)
    float* __restrict__ edge_out)    // (B,N,N)
{
    __shared__ float E_s[TI][TJ][12];               // 12 KiB, padded rows
    __shared__ float sums_s[BATCH][TI][TJ];         // 2 KiB

    const int t    = threadIdx.x;
    const int lane = t & 63;
    const int wave = t >> 6;
    const int bi   = blockIdx.x;
    const int i0   = (bi >> 3) * TI;   // 128 i-blocks
    const int j0   = (bi & 7) * TJ;    // 8 j-blocks

    // Stage E tile with 9->12 padding (rows become 16B-aligned float4 x3).
#pragma unroll
    for (int ii = 0; ii < TI; ++ii) {
        const float* src = &E[((size_t)(i0 + ii) * NN + j0) * EDGE_DIM];
        for (int idx = t; idx < TJ * EDGE_DIM; idx += 512) {
            const int jl = idx / 9;
            const int d  = idx - jl * 9;
            E_s[ii][jl][d] = src[idx];
        }
    }

    // Per-lane weights/activations, h = lane*4 + k.
    float4 wee[EDGE_DIM];
    const float4* We_e4 = (const float4*)We_e;
#pragma unroll
    for (int d = 0; d < EDGE_DIM; ++d) wee[d] = We_e4[d * 64 + lane];
    const float4 w2 = ((const float4*)We2)[lane];

    float4 pir[BATCH][TI];
#pragma unroll
    for (int b = 0; b < BATCH; ++b)
#pragma unroll
        for (int ii = 0; ii < TI; ++ii)
            pir[b][ii] = ((const float4*)pi)[(size_t)(b * NN + i0 + ii) * 64 + lane];

    __syncthreads();

#pragma unroll
    for (int q = 0; q < 8; ++q) {
        const int jl = wave * 8 + q;
        const int j  = j0 + jl;
        float4 pjr[BATCH];
#pragma unroll
        for (int b = 0; b < BATCH; ++b)
            pjr[b] = ((const float4*)pj)[(size_t)(b * NN + j) * 64 + lane];

#pragma unroll
        for (int ii = 0; ii < TI; ++ii) {
            const float* ep = &E_s[ii][jl][0];
            const float4 e0 = *(const float4*)(ep);
            const float4 e4 = *(const float4*)(ep + 4);
            const float  e8 = ep[8];

            float4 pe;
            pe.x = e0.x * wee[0].x; pe.y = e0.x * wee[0].y;
            pe.z = e0.x * wee[0].z; pe.w = e0.x * wee[0].w;
            pe.x = fmaf(e0.y, wee[1].x, pe.x); pe.y = fmaf(e0.y, wee[1].y, pe.y);
            pe.z = fmaf(e0.y, wee[1].z, pe.z); pe.w = fmaf(e0.y, wee[1].w, pe.w);
            pe.x = fmaf(e0.z, wee[2].x, pe.x); pe.y = fmaf(e0.z, wee[2].y, pe.y);
            pe.z = fmaf(e0.z, wee[2].z, pe.z); pe.w = fmaf(e0.z, wee[2].w, pe.w);
            pe.x = fmaf(e0.w, wee[3].x, pe.x); pe.y = fmaf(e0.w, wee[3].y, pe.y);
            pe.z = fmaf(e0.w, wee[3].z, pe.z); pe.w = fmaf(e0.w, wee[3].w, pe.w);
            pe.x = fmaf(e4.x, wee[4].x, pe.x); pe.y = fmaf(e4.x, wee[4].y, pe.y);
            pe.z = fmaf(e4.x, wee[4].z, pe.z); pe.w = fmaf(e4.x, wee[4].w, pe.w);
            pe.x = fmaf(e4.y, wee[5].x, pe.x); pe.y = fmaf(e4.y, wee[5].y, pe.y);
            pe.z = fmaf(e4.y, wee[5].z, pe.z); pe.w = fmaf(e4.y, wee[5].w, pe.w);
            pe.x = fmaf(e4.z, wee[6].x, pe.x); pe.y = fmaf(e4.z, wee[6].y, pe.y);
            pe.z = fmaf(e4.z, wee[6].z, pe.z); pe.w = fmaf(e4.z, wee[6].w, pe.w);
            pe.x = fmaf(e4.w, wee[7].x, pe.x); pe.y = fmaf(e4.w, wee[7].y, pe.y);
            pe.z = fmaf(e4.w, wee[7].z, pe.z); pe.w = fmaf(e4.w, wee[7].w, pe.w);
            pe.x = fmaf(e8, wee[8].x, pe.x); pe.y = fmaf(e8, wee[8].y, pe.y);
            pe.z = fmaf(e8, wee[8].z, pe.z); pe.w = fmaf(e8, wee[8].w, pe.w);

            float acc[BATCH];
#pragma unroll
            for (int b = 0; b < BATCH; ++b) {
                float4 v;
                v.x = fmaxf(pir[b][ii].x + pjr[b].x + pe.x, 0.f);
                v.y = fmaxf(pir[b][ii].y + pjr[b].y + pe.y, 0.f);
                v.z = fmaxf(pir[b][ii].z + pjr[b].z + pe.z, 0.f);
                v.w = fmaxf(pir[b][ii].w + pjr[b].w + pe.w, 0.f);
                acc[b] = fmaf(v.x, w2.x, fmaf(v.y, w2.y, fmaf(v.z, w2.z, v.w * w2.w)));
            }

            // paired butterfly: even lanes -> b=0 sum, odd lanes -> b=1 sum
            float r  = (lane & 1) ? acc[1] : acc[0];
            float o_ = (lane & 1) ? acc[0] : acc[1];
            r += __shfl_xor(o_, 1, 64);
#pragma unroll
            for (int s = 2; s <= 32; s <<= 1) r += __shfl_xor(r, s, 64);
            if (lane < 2) sums_s[lane][ii][jl] = r;
        }
    }
    __syncthreads();

    // Epilogue: one output per thread (512 = BATCH*TI*TJ).
    {
        const int b   = t >> 8;
        const int rem = t & 255;
        const int ii  = rem >> 6;
        const int jl  = rem & 63;
        const int i = i0 + ii, j = j0 + jl;
        const float s = sums_s[b][ii][jl] + be2[0];
        float p = 1.f / (1.f + expf(-s));
        p *= (float)mask[i * NN + j];
        edge_out[((size_t)b * NN + i) * NN + j] = p;
    }
}

extern "C" void kernel_launch(void* const* d_in, const int* in_sizes, int n_in,
                              void* d_out, int out_size, void* d_ws, size_t ws_size,
                              hipStream_t stream) {
    const float* z    = (const float*)d_in[0];   // (B,N,128)
    const float* E    = (const float*)d_in[1];   // (N,N,9)
    const int*   mask = (const int*)  d_in[2];   // (N,N)
    const float* Wo1  = (const float*)d_in[3];
    const float* bo1  = (const float*)d_in[4];
    const float* Wo2  = (const float*)d_in[5];
    const float* bo2  = (const float*)d_in[6];
    const float* We_i = (const float*)d_in[7];
    const float* We_j = (const float*)d_in[8];
    const float* We_e = (const float*)d_in[9];
    const float* be1  = (const float*)d_in[10];
    const float* We2  = (const float*)d_in[11];
    const float* be2  = (const float*)d_in[12];

    float* out_organ = (float*)d_out;                 // (B,N) = 1024
    float* out_edge  = out_organ + BATCH * NN;        // (B,N,N)

    float* pi = (float*)d_ws;                          // (B*N,256)
    float* pj = pi + (size_t)BATCH * NN * HIDDEN;      // (B*N,256)

    hipLaunchKernelGGL(node_proj_kernel,
                       dim3((BATCH * NN) / ROWSN), dim3(256), 0, stream,
                       z, Wo1, bo1, Wo2, bo2, We_i, We_j, be1,
                       out_organ, pi, pj);

    hipLaunchKernelGGL(edge_kernel,
                       dim3((NN / TI) * (NN / TJ)), dim3(512), 0, stream,
                       E, mask, We_e, We2, be2, pi, pj, out_edge);
}